// Round 1
// baseline (289.247 us; speedup 1.0000x reference)
//
#include <hip/hip_runtime.h>
#include <stdint.h>

// Problem constants: B=2, S=2048, H=1024, NH=16, DK=DV=64, M=B*S=4096.
// Pipeline: cast/transpose -> QKV gemm (bf16 MFMA) -> flash attention -> out gemm.
// Workspace requirement: 40 MB (u16 elements): X(8M) + WqkvT(6M) + WoT(2M) + Q/K/V(24M).

typedef unsigned short u16;
typedef __attribute__((ext_vector_type(8))) __bf16 bf16x8;
typedef __attribute__((ext_vector_type(4))) float f32x4;

__device__ __forceinline__ u16 f2bf(float f) {
  union { float f; uint32_t u; } v; v.f = f;
  uint32_t r = v.u + 0x7FFFu + ((v.u >> 16) & 1u);  // RNE
  return (u16)(r >> 16);
}

// async global->LDS, 16B per lane; LDS dest is wave-uniform base + lane*16
__device__ __forceinline__ void gl_lds16(const u16* g, u16* l) {
  auto gp = reinterpret_cast<const __attribute__((address_space(1))) uint32_t*>(
      reinterpret_cast<uintptr_t>(g));
  auto lp = reinterpret_cast<__attribute__((address_space(3))) uint32_t*>(
      reinterpret_cast<uintptr_t>(l));
  __builtin_amdgcn_global_load_lds(gp, lp, 16, 0, 0);
}

// ---------------- prologue kernels ----------------

__global__ void k_cast(const float* __restrict__ src, u16* __restrict__ dst) {
  int idx = (blockIdx.x * 256 + threadIdx.x) * 4;
  const float4 v = *reinterpret_cast<const float4*>(src + idx);
  uint2 o;
  o.x = (uint32_t)f2bf(v.x) | ((uint32_t)f2bf(v.y) << 16);
  o.y = (uint32_t)f2bf(v.z) | ((uint32_t)f2bf(v.w) << 16);
  *reinterpret_cast<uint2*>(dst + idx) = o;
}

// 1024x1024 transpose + cast: dst[c*1024 + r] = bf16(src[r*1024 + c])
__global__ void k_transpose(const float* __restrict__ src, u16* __restrict__ dst) {
  __shared__ float tile[32][33];
  int c0 = blockIdx.x * 32, r0 = blockIdx.y * 32;
  int tx = threadIdx.x, ty = threadIdx.y;  // block (32,8)
#pragma unroll
  for (int i = 0; i < 4; ++i)
    tile[ty + i * 8][tx] = src[(size_t)(r0 + ty + i * 8) * 1024 + c0 + tx];
  __syncthreads();
#pragma unroll
  for (int i = 0; i < 4; ++i)
    dst[(size_t)(c0 + ty + i * 8) * 1024 + r0 + tx] = f2bf(tile[tx][ty + i * 8]);
}

// ---------------- GEMM core: C[128x128] tile of A[M,K] @ Bt[N,K]^T ----------------
// m97 structure: global_load_lds(16B) staging, 2-barrier K-loop, 16x16x32 bf16 MFMA.

__device__ __forceinline__ void gemm_tile_acc(
    const u16* __restrict__ A, const u16* __restrict__ Bt, int K,
    int tm, int tn, u16* As, u16* Bs, f32x4 acc[4][4]) {
  const int t = threadIdx.x, wv = t >> 6, ln = t & 63;
  const int wr = (wv & 1) * 64, wc = (wv >> 1) * 64;
  const int lr = ln & 15, q8 = (ln >> 4) * 8;
  const int srow = ln >> 2, scol = (ln & 3) * 8;  // staging: 16 rows/chunk, 64B rows

  for (int k0 = 0; k0 < K; k0 += 32) {
#pragma unroll
    for (int i = 0; i < 2; ++i) {
      int c = wv + i * 4;  // wave-uniform chunk id, 8 chunks of 1KB per tile
      gl_lds16(A + (size_t)(tm + c * 16 + srow) * K + k0 + scol, As + c * 512 + ln * 8);
      gl_lds16(Bt + (size_t)(tn + c * 16 + srow) * K + k0 + scol, Bs + c * 512 + ln * 8);
    }
    __syncthreads();  // drains vmcnt for global_load_lds
    bf16x8 av[4], bv[4];
#pragma unroll
    for (int m = 0; m < 4; ++m)
      av[m] = *reinterpret_cast<const bf16x8*>(As + (wr + m * 16 + lr) * 32 + q8);
#pragma unroll
    for (int n = 0; n < 4; ++n)
      bv[n] = *reinterpret_cast<const bf16x8*>(Bs + (wc + n * 16 + lr) * 32 + q8);
#pragma unroll
    for (int m = 0; m < 4; ++m)
#pragma unroll
      for (int n = 0; n < 4; ++n)
        acc[m][n] = __builtin_amdgcn_mfma_f32_16x16x32_bf16(av[m], bv[n], acc[m][n], 0, 0, 0);
    __syncthreads();
  }
}

// QKV projection: X[4096,1024] @ WqkvT[3072,1024]^T; scatter to Q/K/V [B,NH,S,64] bf16
__global__ __launch_bounds__(256) void k_qkv(
    const u16* __restrict__ X, const u16* __restrict__ Wt,
    const float* __restrict__ bQ, const float* __restrict__ bK, const float* __restrict__ bV,
    u16* __restrict__ Q, u16* __restrict__ Kd, u16* __restrict__ V) {
  __shared__ __align__(16) u16 As[128 * 32];
  __shared__ __align__(16) u16 Bs[128 * 32];
  f32x4 acc[4][4] = {};
  const int tm = blockIdx.x * 128, tn = blockIdx.y * 128;
  gemm_tile_acc(X, Wt, 1024, tm, tn, As, Bs, acc);

  const int t = threadIdx.x, wv = t >> 6, ln = t & 63;
  const int wr = (wv & 1) * 64, wc = (wv >> 1) * 64;
  const int lr = ln & 15, q4 = (ln >> 4) * 4;
  const int which = tn >> 10;  // 0:Q 1:K 2:V (block-uniform)
  u16* dst = which == 0 ? Q : (which == 1 ? Kd : V);
  const float* bias = which == 0 ? bQ : (which == 1 ? bK : bV);
#pragma unroll
  for (int n = 0; n < 4; ++n) {
    int gc = tn + wc + n * 16 + lr;
    int f = gc & 1023;
    float bb = bias[f];
    int h = f >> 6, dd = f & 63;
#pragma unroll
    for (int m = 0; m < 4; ++m)
#pragma unroll
      for (int r = 0; r < 4; ++r) {
        int gr = tm + wr + m * 16 + q4 + r;           // token index
        int b = gr >> 11, s = gr & 2047;
        dst[((size_t)((b * 16 + h) * 2048 + s)) * 64 + dd] = f2bf(acc[m][n][r] + bb);
      }
  }
}

// Output projection: O[4096,1024] @ WoT[1024,1024]^T + bO -> fp32 out
__global__ __launch_bounds__(256) void k_out(
    const u16* __restrict__ O, const u16* __restrict__ WoT,
    const float* __restrict__ bO, float* __restrict__ out) {
  __shared__ __align__(16) u16 As[128 * 32];
  __shared__ __align__(16) u16 Bs[128 * 32];
  f32x4 acc[4][4] = {};
  const int tm = blockIdx.x * 128, tn = blockIdx.y * 128;
  gemm_tile_acc(O, WoT, 1024, tm, tn, As, Bs, acc);

  const int t = threadIdx.x, wv = t >> 6, ln = t & 63;
  const int wr = (wv & 1) * 64, wc = (wv >> 1) * 64;
  const int lr = ln & 15, q4 = (ln >> 4) * 4;
#pragma unroll
  for (int n = 0; n < 4; ++n) {
    int gc = tn + wc + n * 16 + lr;
    float bb = bO[gc];
#pragma unroll
    for (int m = 0; m < 4; ++m)
#pragma unroll
      for (int r = 0; r < 4; ++r) {
        int gr = tm + wr + m * 16 + q4 + r;
        out[(size_t)gr * 1024 + gc] = acc[m][n][r] + bb;
      }
  }
}

// ---------------- flash attention ----------------
// grid (16, 32): x = q-tile (BQ=128), y = b*NH+h. block 256 (4 waves, 32 q-rows each).
// Per key tile (64 keys): stage K [64][72] row-major, V transposed -> Vt[d][72],
// QK^T MFMA -> mask -> online softmax (quad shuffles) -> P to LDS (A-layout) -> PV MFMA.
__global__ __launch_bounds__(256) void k_attn(
    const u16* __restrict__ Q, const u16* __restrict__ K, const u16* __restrict__ V,
    const int* __restrict__ ids, u16* __restrict__ O) {
  __shared__ __align__(16) u16 Qs[128 * 72];
  __shared__ __align__(16) u16 Ks[64 * 72];
  __shared__ __align__(16) u16 Vt[64 * 72];
  __shared__ __align__(16) u16 Ps[128 * 72];
  __shared__ float kneg[64];

  const int qi = gridDim.x - 1 - blockIdx.x;  // big tiles first (tail-latency heuristic)
  const int bh = blockIdx.y;
  const int bI = bh >> 4, hI = bh & 15;
  const int q0 = qi * 128;
  const size_t hb = (size_t)bh * 2048 * 64;
  const u16* Qg = Q + hb;
  const u16* Kg = K + hb;
  const u16* Vg = V + hb;

  const int t = threadIdx.x, wv = t >> 6, ln = t & 63;
  const int lr = ln & 15, q4 = (ln >> 4) * 4, q8 = (ln >> 4) * 8;
  const int qw = wv * 32;

  // stage Q tile once: 128 rows x 64 cols, padded stride 72
  {
    int r = t >> 1, seg = (t & 1) * 32;
    const uint4* g = reinterpret_cast<const uint4*>(Qg + (size_t)(q0 + r) * 64 + seg);
    uint4* s = reinterpret_cast<uint4*>(Qs + r * 72 + seg);
#pragma unroll
    for (int j = 0; j < 4; ++j) s[j] = g[j];
  }

  float mo[2][4], lo[2][4];
  f32x4 Oc[2][4] = {};
#pragma unroll
  for (int m = 0; m < 2; ++m)
#pragma unroll
    for (int r = 0; r < 4; ++r) { mo[m][r] = -1e30f; lo[m][r] = 0.f; }

  const int jend = 2 * qi + 1;
  for (int j = 0; j <= jend; ++j) {
    const int kb = j * 64;
    __syncthreads();  // prev PV reads done (and Q staged, iter 0)
    if (t < 128) {    // stage K rows
      int s = t >> 1, seg = (t & 1) * 32;
      const uint4* g = reinterpret_cast<const uint4*>(Kg + (size_t)(kb + s) * 64 + seg);
      uint4* d = reinterpret_cast<uint4*>(Ks + s * 72 + seg);
#pragma unroll
      for (int jj = 0; jj < 4; ++jj) d[jj] = g[jj];
      if (t < 64) kneg[t] = (ids[bI * 2048 + kb + t] == 0) ? -1e30f : 0.f;
    } else {          // stage V transposed: Vt[d][s]
      int t2 = t - 128;
      int s = t2 >> 1, seg = (t2 & 1) * 32;
      uint4 vv[4];
      const uint4* g = reinterpret_cast<const uint4*>(Vg + (size_t)(kb + s) * 64 + seg);
#pragma unroll
      for (int jj = 0; jj < 4; ++jj) vv[jj] = g[jj];
      const u16* pv = reinterpret_cast<const u16*>(vv);
#pragma unroll
      for (int e = 0; e < 32; ++e) Vt[(seg + e) * 72 + s] = pv[e];
    }
    __syncthreads();

    // S = Q K^T (scores in C-layout: col=lane&15, row=quad*4+reg)
    f32x4 sc[2][4] = {};
#pragma unroll
    for (int ks = 0; ks < 2; ++ks) {
      bf16x8 aq[2], bk[4];
#pragma unroll
      for (int m = 0; m < 2; ++m)
        aq[m] = *reinterpret_cast<const bf16x8*>(Qs + (qw + m * 16 + lr) * 72 + ks * 32 + q8);
#pragma unroll
      for (int n = 0; n < 4; ++n)
        bk[n] = *reinterpret_cast<const bf16x8*>(Ks + (n * 16 + lr) * 72 + ks * 32 + q8);
#pragma unroll
      for (int m = 0; m < 2; ++m)
#pragma unroll
        for (int n = 0; n < 4; ++n)
          sc[m][n] = __builtin_amdgcn_mfma_f32_16x16x32_bf16(aq[m], bk[n], sc[m][n], 0, 0, 0);
    }

    // mask + online softmax (row stats live in one 16-lane quad)
#pragma unroll
    for (int m = 0; m < 2; ++m) {
#pragma unroll
      for (int n = 0; n < 4; ++n) {
        const int col = kb + n * 16 + lr;
        const float pad = kneg[n * 16 + lr];
#pragma unroll
        for (int r = 0; r < 4; ++r) {
          const int rowg = q0 + qw + m * 16 + q4 + r;
          float v = sc[m][n][r] * 0.125f + pad;
          sc[m][n][r] = (col > rowg) ? -1e30f : v;
        }
      }
#pragma unroll
      for (int r = 0; r < 4; ++r) {
        float vm = fmaxf(fmaxf(sc[m][0][r], sc[m][1][r]), fmaxf(sc[m][2][r], sc[m][3][r]));
        vm = fmaxf(vm, __shfl_xor(vm, 1, 16));
        vm = fmaxf(vm, __shfl_xor(vm, 2, 16));
        vm = fmaxf(vm, __shfl_xor(vm, 4, 16));
        vm = fmaxf(vm, __shfl_xor(vm, 8, 16));
        const float mn = fmaxf(mo[m][r], vm);
        const float al = __expf(mo[m][r] - mn);
        mo[m][r] = mn;
        float ps = 0.f;
#pragma unroll
        for (int n = 0; n < 4; ++n) {
          float p = __expf(sc[m][n][r] - mn);
          sc[m][n][r] = p;
          ps += p;
        }
        ps += __shfl_xor(ps, 1, 16);
        ps += __shfl_xor(ps, 2, 16);
        ps += __shfl_xor(ps, 4, 16);
        ps += __shfl_xor(ps, 8, 16);
        lo[m][r] = lo[m][r] * al + ps;
#pragma unroll
        for (int n = 0; n < 4; ++n) Oc[m][n][r] *= al;
      }
#pragma unroll
      for (int n = 0; n < 4; ++n)
#pragma unroll
        for (int r = 0; r < 4; ++r)
          Ps[(qw + m * 16 + q4 + r) * 72 + n * 16 + lr] = f2bf(sc[m][n][r]);
    }
    __syncthreads();  // order P writes before A-layout reads (cheap safety)

    // O += P V
#pragma unroll
    for (int ks = 0; ks < 2; ++ks) {
      bf16x8 ap[2], bv[4];
#pragma unroll
      for (int m = 0; m < 2; ++m)
        ap[m] = *reinterpret_cast<const bf16x8*>(Ps + (qw + m * 16 + lr) * 72 + ks * 32 + q8);
#pragma unroll
      for (int n = 0; n < 4; ++n)
        bv[n] = *reinterpret_cast<const bf16x8*>(Vt + (n * 16 + lr) * 72 + ks * 32 + q8);
#pragma unroll
      for (int m = 0; m < 2; ++m)
#pragma unroll
        for (int n = 0; n < 4; ++n)
          Oc[m][n] = __builtin_amdgcn_mfma_f32_16x16x32_bf16(ap[m], bv[n], Oc[m][n], 0, 0, 0);
    }
  }

  // normalize + write O as bf16 [token, h*64+d]
#pragma unroll
  for (int m = 0; m < 2; ++m)
#pragma unroll
    for (int n = 0; n < 4; ++n)
#pragma unroll
      for (int r = 0; r < 4; ++r) {
        int row = q0 + qw + m * 16 + q4 + r;
        float v = Oc[m][n][r] / lo[m][r];
        O[((size_t)(bI * 2048 + row)) * 1024 + hI * 64 + n * 16 + lr] = f2bf(v);
      }
}

// ---------------- launch ----------------

extern "C" void kernel_launch(void* const* d_in, const int* in_sizes, int n_in,
                              void* d_out, int out_size, void* d_ws, size_t ws_size,
                              hipStream_t stream) {
  (void)in_sizes; (void)n_in; (void)out_size; (void)ws_size;
  const float* batch = (const float*)d_in[0];
  const int* ids     = (const int*)d_in[1];
  const float* W_Q   = (const float*)d_in[2];
  const float* W_K   = (const float*)d_in[3];
  const float* W_V   = (const float*)d_in[4];
  const float* b_Q   = (const float*)d_in[5];
  const float* b_K   = (const float*)d_in[6];
  const float* b_V   = (const float*)d_in[7];
  const float* W_O   = (const float*)d_in[8];
  const float* b_O   = (const float*)d_in[9];
  float* out = (float*)d_out;

  u16* ws = (u16*)d_ws;  // element (u16) offsets; total 20M u16 = 40 MB
  u16* Xbf   = ws;                       // 4096*1024
  u16* WqkvT = Xbf + 4096 * 1024;        // 3072*1024
  u16* WoT   = WqkvT + 3072 * 1024;      // 1024*1024
  u16* Qb    = WoT + 1024 * 1024;        // 4096*1024
  u16* Kb    = Qb + 4096 * 1024;
  u16* Vb    = Kb + 4096 * 1024;
  u16* Ob    = Xbf;                      // reuse X after QKV gemm

  k_cast<<<4096, 256, 0, stream>>>(batch, Xbf);
  dim3 tb(32, 8), tg(32, 32);
  k_transpose<<<tg, tb, 0, stream>>>(W_Q, WqkvT);
  k_transpose<<<tg, tb, 0, stream>>>(W_K, WqkvT + 1024 * 1024);
  k_transpose<<<tg, tb, 0, stream>>>(W_V, WqkvT + 2 * 1024 * 1024);
  k_transpose<<<tg, tb, 0, stream>>>(W_O, WoT);
  k_qkv<<<dim3(32, 24), 256, 0, stream>>>(Xbf, WqkvT, b_Q, b_K, b_V, Qb, Kb, Vb);
  k_attn<<<dim3(16, 32), 256, 0, stream>>>(Qb, Kb, Vb, ids, Ob);
  k_out<<<dim3(32, 8), 256, 0, stream>>>(Ob, WoT, b_O, out);
}